// Round 8
// baseline (215.227 us; speedup 1.0000x reference)
//
#include <hip/hip_runtime.h>

// TransR scoring: out[b] = -sum_j | (h_head[b]-h_tail[b]) . P_r[:,j] + e_r[j] |
// B=32768, NFEATS=128, RFEATS=64, NUM_RELS=1000.
//
// Round-8: readlane-free XOR-column inner loop + slice-pipelined P staging.
//  - scatter pre-pass (validated r6/r7) buckets rows by relation.
//  - main: 1000 blocks x 512 thr. Lane (jg,p), column-quad cq = jg ^ 4p:
//    the 4 parts read 4 DIFFERENT column-quads of the same 4 n-rows ->
//    P ds_read_b128 conflict-free with zero padding; part-reduce via
//    shfl_xor(20)+shfl_xor(40) (partners provably share a column-quad:
//    (jg^4)^(4(p^1)) == jg^4p).
//  - d in shared D-tile [32][128] (wave-private rows, float2 writes 2-way
//    free, b32 reads = 4 adjacent addrs x 16-way broadcast, conflict-free).
//  - P staged via 4x global_load_lds(16B), each = one 32-row n-slice;
//    compute ladders s_waitcnt vmcnt(3-s) + raw s_barrier per slice, so
//    HBM latency/BW of slices 1-3 hides under slice-0..2 compute.
//    d-loads issue OLDER than P loads -> ladder counts stay exact (m135:
//    waitcnt retires oldest first; younger extras only make it stricter).

#define NFEATS   128
#define RFEATS   64
#define NUM_RELS 1000
#define STRIDE   128   // bucket slots/rel; cnt~Binom(32768,1e-3), 128 = +16.7 sd

#define AS_GLOBAL __attribute__((address_space(1)))
#define AS_SHARED __attribute__((address_space(3)))

__global__ void scatter_kernel(const int* __restrict__ rels,
                               int* __restrict__ cursors,
                               int* __restrict__ bucket, int B) {
    int i = blockIdx.x * blockDim.x + threadIdx.x;
    if (i < B) {
        int r = rels[i];
        int s = atomicAdd(&cursors[r], 1);
        if (s < STRIDE) bucket[(r << 7) + s] = i;
    }
}

__device__ __forceinline__ void reduce_store(const float acc[4][4],
                                             const int rowid[4],
                                             float4 e4, int lane,
                                             float* __restrict__ out) {
#pragma unroll
    for (int rr = 0; rr < 4; ++rr) {
        float a0 = acc[rr][0], a1 = acc[rr][1], a2 = acc[rr][2], a3 = acc[rr][3];
        a0 += __shfl_xor(a0, 20); a0 += __shfl_xor(a0, 40);
        a1 += __shfl_xor(a1, 20); a1 += __shfl_xor(a1, 40);
        a2 += __shfl_xor(a2, 20); a2 += __shfl_xor(a2, 40);
        a3 += __shfl_xor(a3, 20); a3 += __shfl_xor(a3, 40);
        float sv = fabsf(a0 + e4.x) + fabsf(a1 + e4.y)
                 + fabsf(a2 + e4.z) + fabsf(a3 + e4.w);
        sv += __shfl_xor(sv, 1);
        sv += __shfl_xor(sv, 2);
        sv += __shfl_xor(sv, 4);
        sv += __shfl_xor(sv, 8);
        if (lane == rr && rowid[rr] >= 0) out[rowid[rr]] = -sv;
    }
}

__global__ __launch_bounds__(512, 6) void transr_main(
    const float* __restrict__ h_head,
    const float* __restrict__ h_tail,
    const float* __restrict__ rel_emb,
    const float* __restrict__ rel_proj,
    const int*   __restrict__ cursors,
    const int*   __restrict__ bucket,
    float* __restrict__ out)
{
    __shared__ float Plds[NFEATS * RFEATS];   // 32 KB, row-major [n][j]
    __shared__ float Dlds[32][NFEATS];        // 16 KB, [rowslot][n]

    const int r    = blockIdx.x;
    const int tid  = threadIdx.x;              // 512 = 8 waves
    const int w    = tid >> 6;
    const int lane = tid & 63;
    const int jg   = lane & 15;
    const int p    = lane >> 4;
    const int cq   = jg ^ (p << 2);            // xor-rotated column-quad

    int cnt = cursors[r];
    if (cnt > STRIDE) cnt = STRIDE;
    if (cnt == 0) return;                      // uniform exit BEFORE any barrier

    const int* buk = bucket + (r << 7);

    // ---- pass-0 d-phase: issued BEFORE P loads (older vmcnt ops) ----
    int rowid[4];
#pragma unroll
    for (int rr = 0; rr < 4; ++rr) {
        const int li  = (w << 2) + rr;
        const int row = (li < cnt) ? buk[li] : -1;   // wave-uniform (s_load)
        rowid[rr] = row;
        float2 d = make_float2(0.f, 0.f);
        if (row >= 0) {
            const float2 a = *(const float2*)(h_head + (size_t)row * NFEATS + (lane << 1));
            const float2 b = *(const float2*)(h_tail + (size_t)row * NFEATS + (lane << 1));
            d.x = a.x - b.x;
            d.y = a.y - b.y;
        }
        *(float2*)(&Dlds[(w << 2) + rr][lane << 1]) = d;  // wave-private row
    }

    // ---- issue P staging: load "it" covers n-slice [32it, 32it+32) ----
    const float* Psrc = rel_proj + (size_t)r * (NFEATS * RFEATS);
#pragma unroll
    for (int it = 0; it < 4; ++it) {
        const int off = (it * 512 + tid) * 4;
        __builtin_amdgcn_global_load_lds((const AS_GLOBAL void*)(Psrc + off),
                                         (AS_SHARED void*)(Plds + off), 16, 0, 0);
    }
    __builtin_amdgcn_sched_barrier(0);

    float acc[4][4];
#pragma unroll
    for (int rr = 0; rr < 4; ++rr) {
        acc[rr][0] = 0.f; acc[rr][1] = 0.f; acc[rr][2] = 0.f; acc[rr][3] = 0.f;
    }

    const char*  Pb   = (const char*)Plds;
    const int    pcq  = (p << 8) | (cq << 4);   // byte offset inside a P n-row
    const float* drow = &Dlds[w << 2][p];       // + rr*128 + 32s + 4t (words)
    bool havework = ((w << 2) < cnt);           // wave-uniform

    // ---- pass-0 compute: vmcnt-laddered slices (T3/T4; raw s_barrier so
    // the compiler's __syncthreads vmcnt(0)-drain does not kill the ladder) ----
#pragma unroll
    for (int s = 0; s < 4; ++s) {
        if      (s == 0) asm volatile("s_waitcnt vmcnt(3)" ::: "memory");
        else if (s == 1) asm volatile("s_waitcnt vmcnt(2)" ::: "memory");
        else if (s == 2) asm volatile("s_waitcnt vmcnt(1)" ::: "memory");
        else             asm volatile("s_waitcnt vmcnt(0)" ::: "memory");
        __builtin_amdgcn_sched_barrier(0);
        __builtin_amdgcn_s_barrier();
        if (havework) {
#pragma unroll
            for (int t = 0; t < 8; ++t) {
                const float4 pv = *(const float4*)(Pb + s * 8192 + t * 1024 + pcq);
#pragma unroll
                for (int rr = 0; rr < 4; ++rr) {
                    const float dv = drow[rr * 128 + s * 32 + t * 4];
                    acc[rr][0] = fmaf(dv, pv.x, acc[rr][0]);
                    acc[rr][1] = fmaf(dv, pv.y, acc[rr][1]);
                    acc[rr][2] = fmaf(dv, pv.z, acc[rr][2]);
                    acc[rr][3] = fmaf(dv, pv.w, acc[rr][3]);
                }
            }
        }
    }

    const float4 e4 = *(const float4*)(rel_emb + (size_t)r * RFEATS + (cq << 2));

    if (havework) reduce_store(acc, rowid, e4, lane, out);

    // ---- passes >= 1: P fully resident, no barriers needed ----
    for (int base = 32; base < cnt; base += 32) {
#pragma unroll
        for (int rr = 0; rr < 4; ++rr) {
            const int li  = base + (w << 2) + rr;
            const int row = (li < cnt) ? buk[li] : -1;
            rowid[rr] = row;
            float2 d = make_float2(0.f, 0.f);
            if (row >= 0) {
                const float2 a = *(const float2*)(h_head + (size_t)row * NFEATS + (lane << 1));
                const float2 b = *(const float2*)(h_tail + (size_t)row * NFEATS + (lane << 1));
                d.x = a.x - b.x;
                d.y = a.y - b.y;
            }
            *(float2*)(&Dlds[(w << 2) + rr][lane << 1]) = d;  // same-wave RAW ok
        }

        havework = (base + (w << 2) < cnt);
        if (havework) {
#pragma unroll
            for (int rr = 0; rr < 4; ++rr) {
                acc[rr][0] = 0.f; acc[rr][1] = 0.f; acc[rr][2] = 0.f; acc[rr][3] = 0.f;
            }
#pragma unroll
            for (int s = 0; s < 4; ++s) {
#pragma unroll
                for (int t = 0; t < 8; ++t) {
                    const float4 pv = *(const float4*)(Pb + s * 8192 + t * 1024 + pcq);
#pragma unroll
                    for (int rr = 0; rr < 4; ++rr) {
                        const float dv = drow[rr * 128 + s * 32 + t * 4];
                        acc[rr][0] = fmaf(dv, pv.x, acc[rr][0]);
                        acc[rr][1] = fmaf(dv, pv.y, acc[rr][1]);
                        acc[rr][2] = fmaf(dv, pv.z, acc[rr][2]);
                        acc[rr][3] = fmaf(dv, pv.w, acc[rr][3]);
                    }
                }
            }
            reduce_store(acc, rowid, e4, lane, out);
        }
    }
}

extern "C" void kernel_launch(void* const* d_in, const int* in_sizes, int n_in,
                              void* d_out, int out_size, void* d_ws, size_t ws_size,
                              hipStream_t stream) {
    const float* h_head   = (const float*)d_in[0];
    const float* h_tail   = (const float*)d_in[1];
    const int*   rels     = (const int*)d_in[2];
    const float* rel_emb  = (const float*)d_in[3];
    const float* rel_proj = (const float*)d_in[4];
    float* out = (float*)d_out;

    const int B = in_sizes[2];   // 32768

    // ws: cursors[1024] ints | bucket[NUM_RELS*STRIDE] ints
    int* cursors = (int*)d_ws;
    int* bucket  = cursors + 1024;

    hipMemsetAsync(cursors, 0, 1024 * sizeof(int), stream);   // capture-safe
    scatter_kernel<<<(B + 255) / 256, 256, 0, stream>>>(rels, cursors, bucket, B);
    transr_main<<<NUM_RELS, 512, 0, stream>>>(h_head, h_tail, rel_emb, rel_proj,
                                              cursors, bucket, out);
}